// Round 1
// baseline (4900.293 us; speedup 1.0000x reference)
//
#include <hip/hip_runtime.h>
#include <math.h>

#define BB 4
#define HH 128
#define WW 128
#define AA 96
#define DD 128
#define TT 182
#define NP 5
#define ND 5
#define INV_OPN (1.0f/128.0f)

// ---------------- Radon forward: evalop[b,a,d] = sum_t bilinear(primal_bar ch1) / 128
__global__ __launch_bounds__(256) void radon_fwd_k(const float* __restrict__ pbar,
                                                   float* __restrict__ evalop) {
    int idx = blockIdx.x * 256 + threadIdx.x;
    if (idx >= BB * AA * DD) return;
    int d = idx & (DD - 1);
    int a = (idx / DD) % AA;
    int b = idx / (AA * DD);
    float ang = (float)((double)a * M_PI / (double)AA);
    float c = cosf(ang), sn = sinf(ang);
    float s = (float)d - 63.5f;
    const float* img = pbar + (size_t)b * HH * WW * NP;
    float acc = 0.f;
    for (int tt = 0; tt < TT; ++tt) {
        float t = (float)tt - 90.5f;
        float px = s * c - t * sn;
        float py = s * sn + t * c;
        float xi = px + 63.5f;
        float yi = py + 63.5f;
        float x0f = floorf(xi), y0f = floorf(yi);
        float wx = xi - x0f, wy = yi - y0f;
        int x0 = (int)x0f, y0 = (int)y0f;
        int x1 = x0 + 1, y1 = y0 + 1;
        bool xv0 = (x0 >= 0) & (x0 < WW);
        bool xv1 = (x1 >= 0) & (x1 < WW);
        bool yv0 = (y0 >= 0) & (y0 < HH);
        bool yv1 = (y1 >= 0) & (y1 < HH);
        float v00 = 0.f, v01 = 0.f, v10 = 0.f, v11 = 0.f;
        if (yv0 & xv0) v00 = img[(y0 * WW + x0) * NP + 1];
        if (yv0 & xv1) v01 = img[(y0 * WW + x1) * NP + 1];
        if (yv1 & xv0) v10 = img[(y1 * WW + x0) * NP + 1];
        if (yv1 & xv1) v11 = img[(y1 * WW + x1) * NP + 1];
        acc += v00 * (1.f - wy) * (1.f - wx) + v01 * (1.f - wy) * wx
             + v10 * wy * (1.f - wx) + v11 * wy * wx;
    }
    evalop[idx] = acc * INV_OPN;
}

// ---------------- Radon adjoint: out[b,y,x] = sum_a lerp(dual ch0) / 128
__global__ __launch_bounds__(256) void radon_adj_k(const float* __restrict__ dual,
                                                   float* __restrict__ out) {
    __shared__ float cs[AA], ss[AA];
    int tid = threadIdx.x;
    if (tid < AA) {
        float ang = (float)((double)tid * M_PI / (double)AA);
        cs[tid] = cosf(ang);
        ss[tid] = sinf(ang);
    }
    __syncthreads();
    int idx = blockIdx.x * 256 + tid;
    if (idx >= BB * HH * WW) return;
    int x = idx & (WW - 1);
    int y = (idx / WW) & (HH - 1);
    int b = idx / (HH * WW);
    float px = (float)x - 63.5f;
    float py = (float)y - 63.5f;
    const float* sb = dual + (size_t)b * AA * DD * ND;
    float acc = 0.f;
    for (int a = 0; a < AA; ++a) {
        float det = px * cs[a] + py * ss[a] + 63.5f;
        float d0f = floorf(det);
        float w = det - d0f;
        int d0 = (int)d0f;
        int d1 = d0 + 1;
        float v0 = (d0 >= 0 && d0 < DD) ? sb[(a * DD + d0) * ND] : 0.f;
        float v1 = (d1 >= 0 && d1 < DD) ? sb[(a * DD + d1) * ND] : 0.f;
        acc += v0 * (1.f - w) + v1 * w;
    }
    out[idx] = acc * INV_OPN;
}

// ---------------- Generic 3x3 conv, NHWC, HWIO weights, relu
template<int CI, int CO, int SH, int SW>
__global__ __launch_bounds__(256) void conv3x3_relu_k(const float* __restrict__ in,
        const float* __restrict__ w, const float* __restrict__ bias,
        float* __restrict__ out) {
    int idx = blockIdx.x * 256 + threadIdx.x;
    if (idx >= BB * SH * SW * CO) return;
    int co = idx % CO;
    int x = (idx / CO) % SW;
    int y = (idx / (CO * SW)) % SH;
    int b = idx / (CO * SW * SH);
    const float* inb = in + (size_t)b * SH * SW * CI;
    float acc = bias[co];
    #pragma unroll
    for (int ky = 0; ky < 3; ++ky) {
        int yy = y + ky - 1;
        if (yy < 0 || yy >= SH) continue;
        #pragma unroll
        for (int kx = 0; kx < 3; ++kx) {
            int xx = x + kx - 1;
            if (xx < 0 || xx >= SW) continue;
            const float* ip = inb + (yy * SW + xx) * CI;
            const float* wp = w + ((ky * 3 + kx) * CI) * CO + co;
            #pragma unroll
            for (int ci = 0; ci < CI; ++ci) acc = fmaf(ip[ci], wp[ci * CO], acc);
        }
    }
    out[idx] = fmaxf(acc, 0.f);
}

// ---------------- Dual conv1: gathers concat(dual[5], evalop, y) -> 32ch, relu
__global__ __launch_bounds__(256) void conv_dual1_k(const float* __restrict__ dual,
        const float* __restrict__ evalop, const float* __restrict__ yin,
        const float* __restrict__ w, const float* __restrict__ bias,
        float* __restrict__ out) {
    const int CI = 7, CO = 32, SH = AA, SW = DD;
    int idx = blockIdx.x * 256 + threadIdx.x;
    if (idx >= BB * SH * SW * CO) return;
    int co = idx % CO;
    int x = (idx / CO) % SW;
    int y = (idx / (CO * SW)) % SH;
    int b = idx / (CO * SW * SH);
    const float* dualb = dual + (size_t)b * SH * SW * ND;
    const float* evb = evalop + (size_t)b * SH * SW;
    const float* yb = yin + (size_t)b * SH * SW;
    float acc = bias[co];
    #pragma unroll
    for (int ky = 0; ky < 3; ++ky) {
        int yy = y + ky - 1;
        if (yy < 0 || yy >= SH) continue;
        #pragma unroll
        for (int kx = 0; kx < 3; ++kx) {
            int xx = x + kx - 1;
            if (xx < 0 || xx >= SW) continue;
            int pix = yy * SW + xx;
            const float* wp = w + ((ky * 3 + kx) * CI) * CO + co;
            #pragma unroll
            for (int ci = 0; ci < 5; ++ci) acc = fmaf(dualb[pix * ND + ci], wp[ci * CO], acc);
            acc = fmaf(evb[pix], wp[5 * CO], acc);
            acc = fmaf(yb[pix], wp[6 * CO], acc);
        }
    }
    out[idx] = fmaxf(acc, 0.f);
}

// ---------------- Primal conv1: gathers concat(primal[5], evalop_adj) -> 32ch, relu
__global__ __launch_bounds__(256) void conv_prim1_k(const float* __restrict__ primal,
        const float* __restrict__ evadj,
        const float* __restrict__ w, const float* __restrict__ bias,
        float* __restrict__ out) {
    const int CI = 6, CO = 32, SH = HH, SW = WW;
    int idx = blockIdx.x * 256 + threadIdx.x;
    if (idx >= BB * SH * SW * CO) return;
    int co = idx % CO;
    int x = (idx / CO) % SW;
    int y = (idx / (CO * SW)) % SH;
    int b = idx / (CO * SW * SH);
    const float* pb = primal + (size_t)b * SH * SW * NP;
    const float* evb = evadj + (size_t)b * SH * SW;
    float acc = bias[co];
    #pragma unroll
    for (int ky = 0; ky < 3; ++ky) {
        int yy = y + ky - 1;
        if (yy < 0 || yy >= SH) continue;
        #pragma unroll
        for (int kx = 0; kx < 3; ++kx) {
            int xx = x + kx - 1;
            if (xx < 0 || xx >= SW) continue;
            int pix = yy * SW + xx;
            const float* wp = w + ((ky * 3 + kx) * CI) * CO + co;
            #pragma unroll
            for (int ci = 0; ci < 5; ++ci) acc = fmaf(pb[pix * NP + ci], wp[ci * CO], acc);
            acc = fmaf(evb[pix], wp[5 * CO], acc);
        }
    }
    out[idx] = fmaxf(acc, 0.f);
}

// ---------------- Dual conv3: dual += sigma * (conv(hid2) + bias)
__global__ __launch_bounds__(256) void conv_dual3_k(const float* __restrict__ in,
        const float* __restrict__ w, const float* __restrict__ bias,
        const float* __restrict__ sigma_p, float* __restrict__ dual) {
    const int CI = 32, CO = 5, SH = AA, SW = DD;
    int idx = blockIdx.x * 256 + threadIdx.x;
    if (idx >= BB * SH * SW * CO) return;
    int co = idx % CO;
    int x = (idx / CO) % SW;
    int y = (idx / (CO * SW)) % SH;
    int b = idx / (CO * SW * SH);
    const float* inb = in + (size_t)b * SH * SW * CI;
    float acc = bias[co];
    #pragma unroll
    for (int ky = 0; ky < 3; ++ky) {
        int yy = y + ky - 1;
        if (yy < 0 || yy >= SH) continue;
        #pragma unroll
        for (int kx = 0; kx < 3; ++kx) {
            int xx = x + kx - 1;
            if (xx < 0 || xx >= SW) continue;
            const float* ip = inb + (yy * SW + xx) * CI;
            const float* wp = w + ((ky * 3 + kx) * CI) * CO + co;
            #pragma unroll
            for (int ci = 0; ci < CI; ++ci) acc = fmaf(ip[ci], wp[ci * CO], acc);
        }
    }
    dual[idx] = dual[idx] + (*sigma_p) * acc;
}

// ---------------- Primal conv3: primal update + primal_bar extrapolation
__global__ __launch_bounds__(256) void conv_prim3_k(const float* __restrict__ in,
        const float* __restrict__ w, const float* __restrict__ bias,
        const float* __restrict__ tau_p, const float* __restrict__ theta_p,
        float* __restrict__ primal, float* __restrict__ primal_bar) {
    const int CI = 32, CO = 5, SH = HH, SW = WW;
    int idx = blockIdx.x * 256 + threadIdx.x;
    if (idx >= BB * SH * SW * CO) return;
    int co = idx % CO;
    int x = (idx / CO) % SW;
    int y = (idx / (CO * SW)) % SH;
    int b = idx / (CO * SW * SH);
    const float* inb = in + (size_t)b * SH * SW * CI;
    float acc = bias[co];
    #pragma unroll
    for (int ky = 0; ky < 3; ++ky) {
        int yy = y + ky - 1;
        if (yy < 0 || yy >= SH) continue;
        #pragma unroll
        for (int kx = 0; kx < 3; ++kx) {
            int xx = x + kx - 1;
            if (xx < 0 || xx >= SW) continue;
            const float* ip = inb + (yy * SW + xx) * CI;
            const float* wp = w + ((ky * 3 + kx) * CI) * CO + co;
            #pragma unroll
            for (int ci = 0; ci < CI; ++ci) acc = fmaf(ip[ci], wp[ci * CO], acc);
        }
    }
    float pold = primal[idx];
    float pn = pold + (*tau_p) * acc;
    primal[idx] = pn;
    primal_bar[idx] = pn + (*theta_p) * (pn - pold);
}

// ---------------- Extract channel 0 of primal
__global__ __launch_bounds__(256) void extract_k(const float* __restrict__ primal,
                                                 float* __restrict__ out) {
    int idx = blockIdx.x * 256 + threadIdx.x;
    if (idx >= BB * HH * WW) return;
    out[idx] = primal[idx * NP];
}

extern "C" void kernel_launch(void* const* d_in, const int* in_sizes, int n_in,
                              void* d_out, int out_size, void* d_ws, size_t ws_size,
                              hipStream_t stream) {
    const float* y     = (const float*)d_in[0];
    const float* sigma = (const float*)d_in[1];
    const float* tau   = (const float*)d_in[2];
    const float* theta = (const float*)d_in[3];
    const float* dw1 = (const float*)d_in[4];
    const float* db1 = (const float*)d_in[5];
    const float* dw2 = (const float*)d_in[6];
    const float* db2 = (const float*)d_in[7];
    const float* dw3 = (const float*)d_in[8];
    const float* db3 = (const float*)d_in[9];
    const float* pw1 = (const float*)d_in[10];
    const float* pb1 = (const float*)d_in[11];
    const float* pw2 = (const float*)d_in[12];
    const float* pb2 = (const float*)d_in[13];
    const float* pw3 = (const float*)d_in[14];
    const float* pb3 = (const float*)d_in[15];

    float* ws = (float*)d_ws;
    float* primal     = ws;                         // B*H*W*5   = 327680
    float* primal_bar = primal + BB*HH*WW*NP;       // 327680
    float* dual       = primal_bar + BB*HH*WW*NP;   // B*A*D*5   = 245760
    float* evalop     = dual + BB*AA*DD*ND;         // B*A*D     = 49152
    float* evalop_adj = evalop + BB*AA*DD;          // B*H*W     = 65536
    float* hid1       = evalop_adj + BB*HH*WW;      // B*H*W*32  = 2097152
    float* hid2       = hid1 + BB*HH*WW*32;         // 2097152

    // zero state buffers (primal, primal_bar, dual are contiguous)
    hipMemsetAsync(primal, 0, (size_t)(2 * BB*HH*WW*NP + BB*AA*DD*ND) * sizeof(float), stream);

    for (int it = 0; it < 10; ++it) {
        radon_fwd_k<<<(BB*AA*DD)/256, 256, 0, stream>>>(primal_bar, evalop);
        conv_dual1_k<<<(BB*AA*DD*32)/256, 256, 0, stream>>>(dual, evalop, y, dw1, db1, hid1);
        conv3x3_relu_k<32,32,AA,DD><<<(BB*AA*DD*32)/256, 256, 0, stream>>>(hid1, dw2, db2, hid2);
        conv_dual3_k<<<(BB*AA*DD*5)/256, 256, 0, stream>>>(hid2, dw3, db3, sigma, dual);
        radon_adj_k<<<(BB*HH*WW)/256, 256, 0, stream>>>(dual, evalop_adj);
        conv_prim1_k<<<(BB*HH*WW*32)/256, 256, 0, stream>>>(primal, evalop_adj, pw1, pb1, hid1);
        conv3x3_relu_k<32,32,HH,WW><<<(BB*HH*WW*32)/256, 256, 0, stream>>>(hid1, pw2, pb2, hid2);
        conv_prim3_k<<<(BB*HH*WW*5)/256, 256, 0, stream>>>(hid2, pw3, pb3, tau, theta, primal, primal_bar);
    }
    extract_k<<<(BB*HH*WW)/256, 256, 0, stream>>>(primal, (float*)d_out);
}

// Round 2
// 1165.383 us; speedup vs baseline: 4.2049x; 4.2049x over previous
//
#include <hip/hip_runtime.h>
#include <math.h>

#define BB 4
#define HHH 128
#define WWW 128
#define AANG 96
#define DDET 128
#define TSTEP 182
#define M_P (BB*HHH*WWW)   // 65536
#define M_D (BB*AANG*DDET) // 49152
#define INV_OPN (1.0f/128.0f)

typedef __bf16 bf16x8 __attribute__((ext_vector_type(8)));
typedef float  f32x4  __attribute__((ext_vector_type(4)));

__device__ __forceinline__ void split_store(__bf16* hi, __bf16* lo, int off, float v) {
    __bf16 h = (__bf16)v;
    hi[off] = h;
    lo[off] = (__bf16)(v - (float)h);
}

// ================= conv core: implicit GEMM, 16x16x32 bf16 MFMA, bf16x3 split =================
// A: [M][CIP] activations (hi/lo), pixels linear over [B, IH, 128]
// W: [taps_pad][COP][CIP] transposed weights (hi/lo), zero-padded
// K enumerated tap-major: k = tap*CIP + ci. CIP=32 -> chunk==tap; CIP=8 -> chunk covers 4 taps.
template<int CIP, int NCH, int NCOT, int IH>
__device__ __forceinline__ void conv_core(
        const __bf16* __restrict__ Ahi, const __bf16* __restrict__ Alo,
        const __bf16* __restrict__ Whi, const __bf16* __restrict__ Wlo,
        int mtile, f32x4 acc[NCOT])
{
    const int IW = 128;
    const int COP = NCOT * 16;
    int lane = threadIdx.x & 63;
    int n16  = lane & 15;
    int quad = lane >> 4;
    int p0  = mtile * 16;
    int b   = p0 / (IH * IW);
    int rem = p0 - b * (IH * IW);
    int ty  = rem >> 7;
    int tx0 = rem & 127;
    #pragma unroll
    for (int c = 0; c < NCH; ++c) {
        int tap = (CIP == 32) ? c : (c * 4 + quad);
        int dy = tap / 3 - 1;
        int dx = tap % 3 - 1;
        int yy = ty + dy;
        int xx = tx0 + n16 + dx;
        bool valid = (tap < 9) && (yy >= 0) && (yy < IH) && (xx >= 0) && (xx < IW);
        bf16x8 a_h = {};
        bf16x8 a_l = {};
        if (valid) {
            size_t off = (size_t)(b * IH * IW + yy * IW + xx) * CIP
                       + ((CIP == 32) ? (quad * 8) : 0);
            a_h = *(const bf16x8*)(Ahi + off);
            a_l = *(const bf16x8*)(Alo + off);
        }
        #pragma unroll
        for (int ct = 0; ct < NCOT; ++ct) {
            size_t woff = ((size_t)tap * COP + ct * 16 + n16) * CIP
                        + ((CIP == 32) ? (quad * 8) : 0);
            bf16x8 b_h = *(const bf16x8*)(Whi + woff);
            bf16x8 b_l = *(const bf16x8*)(Wlo + woff);
            acc[ct] = __builtin_amdgcn_mfma_f32_16x16x32_bf16(a_h, b_h, acc[ct], 0, 0, 0);
            acc[ct] = __builtin_amdgcn_mfma_f32_16x16x32_bf16(a_h, b_l, acc[ct], 0, 0, 0);
            acc[ct] = __builtin_amdgcn_mfma_f32_16x16x32_bf16(a_l, b_h, acc[ct], 0, 0, 0);
        }
    }
}

// conv1 / conv2: bias + relu -> hid hi/lo [M][32]
template<int CIP, int NCH, int IH>
__global__ __launch_bounds__(256) void conv_ab_k(
        const __bf16* __restrict__ Ahi, const __bf16* __restrict__ Alo,
        const __bf16* __restrict__ Whi, const __bf16* __restrict__ Wlo,
        const float* __restrict__ bias,
        __bf16* __restrict__ Ohi, __bf16* __restrict__ Olo, int Mtiles)
{
    int wid = (blockIdx.x * 256 + threadIdx.x) >> 6;
    if (wid >= Mtiles) return;
    f32x4 acc[2] = {};
    conv_core<CIP, NCH, 2, IH>(Ahi, Alo, Whi, Wlo, wid, acc);
    int lane = threadIdx.x & 63;
    int n16 = lane & 15;
    int quad = lane >> 4;
    #pragma unroll
    for (int ct = 0; ct < 2; ++ct) {
        float bv = bias[ct * 16 + n16];
        #pragma unroll
        for (int r = 0; r < 4; ++r) {
            float v = acc[ct][r] + bv;
            v = fmaxf(v, 0.f);
            int m = wid * 16 + quad * 4 + r;
            split_store(Ohi, Olo, m * 32 + ct * 16 + n16, v);
        }
    }
}

// conv3 dual: dual_f += sigma*(acc+bias); write cat_d ch0-4 hi/lo; dual0 packed (co==0)
template<int IH>
__global__ __launch_bounds__(256) void conv_c_dual_k(
        const __bf16* __restrict__ Ahi, const __bf16* __restrict__ Alo,
        const __bf16* __restrict__ Whi, const __bf16* __restrict__ Wlo,
        const float* __restrict__ bias, const float* __restrict__ sigma_p,
        float* __restrict__ dual_f, __bf16* __restrict__ cat_hi, __bf16* __restrict__ cat_lo,
        float* __restrict__ dual0, int Mtiles)
{
    int wid = (blockIdx.x * 256 + threadIdx.x) >> 6;
    if (wid >= Mtiles) return;
    f32x4 acc[1] = {};
    conv_core<32, 9, 1, IH>(Ahi, Alo, Whi, Wlo, wid, acc);
    int lane = threadIdx.x & 63;
    int n16 = lane & 15;
    int quad = lane >> 4;
    if (n16 < 5) {
        float sg = *sigma_p;
        float bv = bias[n16];
        #pragma unroll
        for (int r = 0; r < 4; ++r) {
            int m = wid * 16 + quad * 4 + r;
            float v = acc[0][r] + bv;
            float dn = dual_f[m * 5 + n16] + sg * v;
            dual_f[m * 5 + n16] = dn;
            split_store(cat_hi, cat_lo, m * 8 + n16, dn);
            if (n16 == 0) dual0[m] = dn;
        }
    }
}

// conv3 primal: primal update + pbar ch1
template<int IH>
__global__ __launch_bounds__(256) void conv_c_prim_k(
        const __bf16* __restrict__ Ahi, const __bf16* __restrict__ Alo,
        const __bf16* __restrict__ Whi, const __bf16* __restrict__ Wlo,
        const float* __restrict__ bias, const float* __restrict__ tau_p,
        const float* __restrict__ theta_p,
        float* __restrict__ primal_f, __bf16* __restrict__ cat_hi, __bf16* __restrict__ cat_lo,
        float* __restrict__ pbar1, int Mtiles)
{
    int wid = (blockIdx.x * 256 + threadIdx.x) >> 6;
    if (wid >= Mtiles) return;
    f32x4 acc[1] = {};
    conv_core<32, 9, 1, IH>(Ahi, Alo, Whi, Wlo, wid, acc);
    int lane = threadIdx.x & 63;
    int n16 = lane & 15;
    int quad = lane >> 4;
    if (n16 < 5) {
        float ta = *tau_p;
        float th = *theta_p;
        float bv = bias[n16];
        #pragma unroll
        for (int r = 0; r < 4; ++r) {
            int m = wid * 16 + quad * 4 + r;
            float v = acc[0][r] + bv;
            float pold = primal_f[m * 5 + n16];
            float pn = pold + ta * v;
            primal_f[m * 5 + n16] = pn;
            split_store(cat_hi, cat_lo, m * 8 + n16, pn);
            if (n16 == 1) pbar1[m] = pn + th * (pn - pold);
        }
    }
}

// ================= Radon forward (t-split x4 partials) =================
__global__ __launch_bounds__(256) void radon_fwd_part_k(const float* __restrict__ img,
                                                        float* __restrict__ part)
{
    int idx = blockIdx.x * 256 + threadIdx.x;      // 4*M_D
    int q = idx / M_D;
    int pix = idx - q * M_D;
    int d = pix & 127;
    int b = pix / (AANG * DDET);
    int a = (pix - b * AANG * DDET) >> 7;
    float ang = (float)((double)a * M_PI / (double)AANG);
    float c = cosf(ang), sn = sinf(ang);
    float s = (float)d - 63.5f;
    float scx = s * c, ssy = s * sn;
    const float* ib = img + b * (HHH * WWW);
    float acc = 0.f;
    int t0 = q * 46;
    int t1 = t0 + 46 < TSTEP ? t0 + 46 : TSTEP;
    for (int tt = t0; tt < t1; ++tt) {
        float t = (float)tt - 90.5f;
        float xi = (scx - t * sn) + 63.5f;
        float yi = (ssy + t * c) + 63.5f;
        float x0f = floorf(xi), y0f = floorf(yi);
        float wx = xi - x0f, wy = yi - y0f;
        int x0 = (int)x0f, y0 = (int)y0f;
        int x1 = x0 + 1, y1 = y0 + 1;
        bool xv0 = (x0 >= 0) & (x0 < WWW);
        bool xv1 = (x1 >= 0) & (x1 < WWW);
        bool yv0 = (y0 >= 0) & (y0 < HHH);
        bool yv1 = (y1 >= 0) & (y1 < HHH);
        float v00 = (yv0 & xv0) ? ib[y0 * WWW + x0] : 0.f;
        float v01 = (yv0 & xv1) ? ib[y0 * WWW + x1] : 0.f;
        float v10 = (yv1 & xv0) ? ib[y1 * WWW + x0] : 0.f;
        float v11 = (yv1 & xv1) ? ib[y1 * WWW + x1] : 0.f;
        acc += v00 * (1.f - wy) * (1.f - wx) + v01 * (1.f - wy) * wx
             + v10 * wy * (1.f - wx) + v11 * wy * wx;
    }
    part[idx] = acc;
}

__global__ __launch_bounds__(256) void fwd_combine_k(const float* __restrict__ part,
                                                     __bf16* __restrict__ cat_hi,
                                                     __bf16* __restrict__ cat_lo)
{
    int pix = blockIdx.x * 256 + threadIdx.x;
    if (pix >= M_D) return;
    float v = (part[pix] + part[M_D + pix] + part[2 * M_D + pix] + part[3 * M_D + pix]) * INV_OPN;
    split_store(cat_hi, cat_lo, pix * 8 + 5, v);
}

// ================= Radon adjoint (a-split x2 partials) =================
__global__ __launch_bounds__(256) void radon_adj_part_k(const float* __restrict__ sino0,
                                                        float* __restrict__ part)
{
    __shared__ float cs[AANG], ss[AANG];
    int tid = threadIdx.x;
    if (tid < AANG) {
        double ang = (double)tid * M_PI / (double)AANG;
        cs[tid] = (float)cos(ang);
        ss[tid] = (float)sin(ang);
    }
    __syncthreads();
    int idx = blockIdx.x * 256 + tid;               // 2*M_P
    int h = idx >> 16;
    int pix = idx & (M_P - 1);
    int x = pix & 127;
    int yv = (pix >> 7) & 127;
    int b = pix >> 14;
    float px = (float)x - 63.5f;
    float py = (float)yv - 63.5f;
    const float* sb = sino0 + b * (AANG * DDET);
    float acc = 0.f;
    int a0 = h * 48;
    for (int a = a0; a < a0 + 48; ++a) {
        float det = px * cs[a] + py * ss[a] + 63.5f;
        float dh = floorf(det);
        float w = det - dh;
        int d0 = (int)dh;
        int d1 = d0 + 1;
        float v0 = (d0 >= 0 && d0 < DDET) ? sb[a * DDET + d0] : 0.f;
        float v1 = (d1 >= 0 && d1 < DDET) ? sb[a * DDET + d1] : 0.f;
        acc += v0 * (1.f - w) + v1 * w;
    }
    part[idx] = acc;
}

__global__ __launch_bounds__(256) void adj_combine_k(const float* __restrict__ part,
                                                     __bf16* __restrict__ cat_hi,
                                                     __bf16* __restrict__ cat_lo)
{
    int pix = blockIdx.x * 256 + threadIdx.x;
    if (pix >= M_P) return;
    float v = (part[pix] + part[M_P + pix]) * INV_OPN;
    split_store(cat_hi, cat_lo, pix * 8 + 5, v);
}

// ================= setup kernels =================
__global__ __launch_bounds__(256) void y_conv_k(const float* __restrict__ y,
                                                __bf16* __restrict__ cat_hi,
                                                __bf16* __restrict__ cat_lo)
{
    int pix = blockIdx.x * 256 + threadIdx.x;
    if (pix >= M_D) return;
    split_store(cat_hi, cat_lo, pix * 8 + 6, y[pix]);
}

// transpose+split weights: src HWIO [tap][ci][co] -> dst [tap_pad][co_pad][ci_pad] hi/lo
__global__ __launch_bounds__(256) void prep_w_k(
        const float* __restrict__ dw1, const float* __restrict__ dw2, const float* __restrict__ dw3,
        const float* __restrict__ pw1, const float* __restrict__ pw2, const float* __restrict__ pw3,
        __bf16* __restrict__ wT)
{
    __bf16* d1h = wT;            __bf16* d1l = d1h + 3072;
    __bf16* d2h = d1l + 3072;    __bf16* d2l = d2h + 9216;
    __bf16* d3h = d2l + 9216;    __bf16* d3l = d3h + 4608;
    __bf16* p1h = d3l + 4608;    __bf16* p1l = p1h + 3072;
    __bf16* p2h = p1l + 3072;    __bf16* p2l = p2h + 9216;
    __bf16* p3h = p2l + 9216;    __bf16* p3l = p3h + 4608;
    int i = blockIdx.x * 256 + threadIdx.x;
    if (i < 2016) {                 // dw1: CI=7 CO=32 -> [12][32][8]
        int co = i & 31; int r = i >> 5; int ci = r % 7; int tap = r / 7;
        split_store(d1h, d1l, (tap * 32 + co) * 8 + ci, dw1[i]);
        return;
    }
    i -= 2016;
    if (i < 9216) {                 // dw2: CI=32 CO=32 -> [9][32][32]
        int co = i & 31; int r = i >> 5; int ci = r & 31; int tap = r >> 5;
        split_store(d2h, d2l, (tap * 32 + co) * 32 + ci, dw2[i]);
        return;
    }
    i -= 9216;
    if (i < 1440) {                 // dw3: CI=32 CO=5 -> [9][16][32]
        int co = i % 5; int r = i / 5; int ci = r & 31; int tap = r >> 5;
        split_store(d3h, d3l, (tap * 16 + co) * 32 + ci, dw3[i]);
        return;
    }
    i -= 1440;
    if (i < 1728) {                 // pw1: CI=6 CO=32 -> [12][32][8]
        int co = i & 31; int r = i >> 5; int ci = r % 6; int tap = r / 6;
        split_store(p1h, p1l, (tap * 32 + co) * 8 + ci, pw1[i]);
        return;
    }
    i -= 1728;
    if (i < 9216) {                 // pw2
        int co = i & 31; int r = i >> 5; int ci = r & 31; int tap = r >> 5;
        split_store(p2h, p2l, (tap * 32 + co) * 32 + ci, pw2[i]);
        return;
    }
    i -= 9216;
    if (i < 1440) {                 // pw3
        int co = i % 5; int r = i / 5; int ci = r & 31; int tap = r >> 5;
        split_store(p3h, p3l, (tap * 16 + co) * 32 + ci, pw3[i]);
        return;
    }
}

__global__ __launch_bounds__(256) void extract_k(const float* __restrict__ primal_f,
                                                 float* __restrict__ out)
{
    int pix = blockIdx.x * 256 + threadIdx.x;
    if (pix >= M_P) return;
    out[pix] = primal_f[pix * 5];
}

extern "C" void kernel_launch(void* const* d_in, const int* in_sizes, int n_in,
                              void* d_out, int out_size, void* d_ws, size_t ws_size,
                              hipStream_t stream) {
    const float* y     = (const float*)d_in[0];
    const float* sigma = (const float*)d_in[1];
    const float* tau   = (const float*)d_in[2];
    const float* theta = (const float*)d_in[3];
    const float* dw1 = (const float*)d_in[4];
    const float* db1 = (const float*)d_in[5];
    const float* dw2 = (const float*)d_in[6];
    const float* db2 = (const float*)d_in[7];
    const float* dw3 = (const float*)d_in[8];
    const float* db3 = (const float*)d_in[9];
    const float* pw1 = (const float*)d_in[10];
    const float* pb1 = (const float*)d_in[11];
    const float* pw2 = (const float*)d_in[12];
    const float* pb2 = (const float*)d_in[13];
    const float* pw3 = (const float*)d_in[14];
    const float* pb3 = (const float*)d_in[15];

    float* ws = (float*)d_ws;
    float* primal_f = ws;                    // M_P*5
    float* dual_f   = primal_f + M_P * 5;    // M_D*5
    float* pbar1    = dual_f + M_D * 5;      // M_P
    float* dual0    = pbar1 + M_P;           // M_D
    float* fwd_part = dual0 + M_D;           // 4*M_D
    float* adj_part = fwd_part + 4 * M_D;    // 2*M_P
    __bf16* bf = (__bf16*)(adj_part + 2 * M_P);
    __bf16* cat_d_hi = bf;                   // M_D*8
    __bf16* cat_d_lo = cat_d_hi + M_D * 8;
    __bf16* cat_p_hi = cat_d_lo + M_D * 8;   // M_P*8
    __bf16* cat_p_lo = cat_p_hi + M_P * 8;
    __bf16* hidA_hi  = cat_p_lo + M_P * 8;   // M_P*32 each
    __bf16* hidA_lo  = hidA_hi + M_P * 32;
    __bf16* hidB_hi  = hidA_lo + M_P * 32;
    __bf16* hidB_lo  = hidB_hi + M_P * 32;
    __bf16* wT       = hidB_lo + M_P * 32;   // 67584

    __bf16* d1h = wT;            __bf16* d1l = d1h + 3072;
    __bf16* d2h = d1l + 3072;    __bf16* d2l = d2h + 9216;
    __bf16* d3h = d2l + 9216;    __bf16* d3l = d3h + 4608;
    __bf16* p1h = d3l + 4608;    __bf16* p1l = p1h + 3072;
    __bf16* p2h = p1l + 3072;    __bf16* p2l = p2h + 9216;
    __bf16* p3h = p2l + 9216;    __bf16* p3l = p3h + 4608;

    // zero: fp32 state (primal, dual, pbar1); cat buffers (pad channels); weights (pad)
    hipMemsetAsync(primal_f, 0, (size_t)(M_P * 5 + M_D * 5 + M_P) * 4, stream);
    hipMemsetAsync(cat_d_hi, 0, (size_t)(M_D * 16 + M_P * 16) * 2, stream);
    hipMemsetAsync(wT, 0, (size_t)67584 * 2, stream);

    prep_w_k<<<98, 256, 0, stream>>>(dw1, dw2, dw3, pw1, pw2, pw3, wT);
    y_conv_k<<<M_D / 256, 256, 0, stream>>>(y, cat_d_hi, cat_d_lo);

    const int MT_D = M_D / 16;   // 3072
    const int MT_P = M_P / 16;   // 4096

    for (int it = 0; it < 10; ++it) {
        radon_fwd_part_k<<<4 * M_D / 256, 256, 0, stream>>>(pbar1, fwd_part);
        fwd_combine_k<<<M_D / 256, 256, 0, stream>>>(fwd_part, cat_d_hi, cat_d_lo);
        conv_ab_k<8, 3, AANG><<<MT_D / 4, 256, 0, stream>>>(cat_d_hi, cat_d_lo, d1h, d1l, db1, hidA_hi, hidA_lo, MT_D);
        conv_ab_k<32, 9, AANG><<<MT_D / 4, 256, 0, stream>>>(hidA_hi, hidA_lo, d2h, d2l, db2, hidB_hi, hidB_lo, MT_D);
        conv_c_dual_k<AANG><<<MT_D / 4, 256, 0, stream>>>(hidB_hi, hidB_lo, d3h, d3l, db3, sigma, dual_f, cat_d_hi, cat_d_lo, dual0, MT_D);
        radon_adj_part_k<<<2 * M_P / 256, 256, 0, stream>>>(dual0, adj_part);
        adj_combine_k<<<M_P / 256, 256, 0, stream>>>(adj_part, cat_p_hi, cat_p_lo);
        conv_ab_k<8, 3, HHH><<<MT_P / 4, 256, 0, stream>>>(cat_p_hi, cat_p_lo, p1h, p1l, pb1, hidA_hi, hidA_lo, MT_P);
        conv_ab_k<32, 9, HHH><<<MT_P / 4, 256, 0, stream>>>(hidA_hi, hidA_lo, p2h, p2l, pb2, hidB_hi, hidB_lo, MT_P);
        conv_c_prim_k<HHH><<<MT_P / 4, 256, 0, stream>>>(hidB_hi, hidB_lo, p3h, p3l, pb3, tau, theta, primal_f, cat_p_hi, cat_p_lo, pbar1, MT_P);
    }
    extract_k<<<M_P / 256, 256, 0, stream>>>(primal_f, (float*)d_out);
}